// Round 1
// baseline (481.987 us; speedup 1.0000x reference)
//
#include <hip/hip_runtime.h>

#define WPB 4   // waves (=races) per block
#define H 64

__global__ __launch_bounds__(WPB * 64)
void prl_races(const float* __restrict__ scores,
               const int* __restrict__ rankings,
               const int* __restrict__ mask,
               float* __restrict__ acc, int B)
{
    __shared__ float4 smem[WPB][H / 2];   // per wave: 64 x {s, key} packed as float4 pairs

    const int lane = threadIdx.x & 63;
    const int wv   = threadIdx.x >> 6;
    const int race = blockIdx.x * WPB + wv;
    const bool active = race < B;

    float s = 0.0f;
    int key = 0;
    if (active) {
        const int idx = race * H + lane;
        s = scores[idx];
        const int r = rankings[idx];
        const int m = mask[idx];
        key = (m != 0 && r > 0) ? r : 0;
    }

    // stage this race's (score, key) into LDS, 8B per lane
    float2* sm2 = reinterpret_cast<float2*>(&smem[wv][0]);
    sm2[lane] = make_float2(s, __int_as_float(key));
    __syncthreads();

    float sum = 0.0f, cnt = 0.0f;
    #pragma unroll
    for (int jj = 0; jj < H / 2; ++jj) {
        const float4 p = smem[wv][jj];            // wave-uniform -> LDS broadcast
        const int k0 = __float_as_int(p.y);
        const int k1 = __float_as_int(p.w);
        const float h0 = fmaxf(1.0f - s + p.x, 0.0f);
        const float h1 = fmaxf(1.0f - s + p.z, 0.0f);
        if (key < k0) { sum += h0; cnt += 1.0f; }
        if (key < k1) { sum += h1; cnt += 1.0f; }
    }
    if (key == 0) { sum = 0.0f; cnt = 0.0f; }     // invalid-i lanes contribute nothing

    // wave64 reduction
    #pragma unroll
    for (int off = 32; off > 0; off >>= 1) {
        sum += __shfl_down(sum, off, 64);
        cnt += __shfl_down(cnt, off, 64);
    }

    if (active && lane == 0 && cnt > 0.0f) {
        atomicAdd(&acc[0], sum / cnt);   // per-race normalized loss
        atomicAdd(&acc[1], 1.0f);        // races contributing to the mean
    }
}

__global__ void prl_final(const float* __restrict__ acc, float* __restrict__ out)
{
    const float n = acc[1];
    out[0] = (n > 0.0f) ? acc[0] / n : 0.0f;
}

extern "C" void kernel_launch(void* const* d_in, const int* in_sizes, int n_in,
                              void* d_out, int out_size, void* d_ws, size_t ws_size,
                              hipStream_t stream)
{
    const float* scores   = (const float*)d_in[0];
    const int*   rankings = (const int*)d_in[1];
    const int*   mask     = (const int*)d_in[2];
    const int B = in_sizes[0] / H;

    float* acc = (float*)d_ws;
    hipMemsetAsync(acc, 0, 2 * sizeof(float), stream);

    const int grid = (B + WPB - 1) / WPB;
    prl_races<<<grid, WPB * 64, 0, stream>>>(scores, rankings, mask, acc, B);
    prl_final<<<1, 1, 0, stream>>>(acc, (float*)d_out);
}

// Round 2
// 76.560 us; speedup vs baseline: 6.2955x; 6.2955x over previous
//
#include <hip/hip_runtime.h>

#define H 64
#define WPB 4          // waves per block
#define BLOCKS 1024    // 4096 waves total -> 4 races per wave at B=16384

__global__ __launch_bounds__(WPB * 64)
void prl_races(const float* __restrict__ scores,
               const int* __restrict__ rankings,
               const int* __restrict__ mask,
               float2* __restrict__ partial, int B)
{
    __shared__ float4 smem[WPB][H / 2];   // per wave: 64 x {s, key} packed
    __shared__ float wsum[WPB], wcnt[WPB];

    const int lane   = threadIdx.x & 63;
    const int wv     = threadIdx.x >> 6;
    const int gwave  = blockIdx.x * WPB + wv;
    const int nwaves = gridDim.x * WPB;
    const int iters  = (B + nwaves - 1) / nwaves;   // uniform across block

    float loc_sum = 0.0f, loc_has = 0.0f;

    for (int it = 0; it < iters; ++it) {
        const int race  = gwave + it * nwaves;
        const bool act  = race < B;

        float s = 0.0f;
        int key = 0;
        if (act) {
            const int idx = race * H + lane;
            s = scores[idx];
            const int r = rankings[idx];
            const int m = mask[idx];
            key = (m != 0 && r > 0) ? r : 0;
        }

        float2* sm2 = reinterpret_cast<float2*>(&smem[wv][0]);
        sm2[lane] = make_float2(s, __int_as_float(key));
        __syncthreads();

        const float t = 1.0f - s;            // hinge = max(t + s_j, 0)
        float sum = 0.0f, cnt = 0.0f;
        #pragma unroll
        for (int jj = 0; jj < H / 2; ++jj) {
            const float4 p = smem[wv][jj];   // wave-uniform -> LDS broadcast
            const int k0 = __float_as_int(p.y);
            const int k1 = __float_as_int(p.w);
            const float h0 = fmaxf(t + p.x, 0.0f);
            const float h1 = fmaxf(t + p.z, 0.0f);
            if (key < k0) { sum += h0; cnt += 1.0f; }
            if (key < k1) { sum += h1; cnt += 1.0f; }
        }
        if (key == 0) { sum = 0.0f; cnt = 0.0f; }  // invalid-i lanes

        // wave64 reduction
        #pragma unroll
        for (int off = 32; off > 0; off >>= 1) {
            sum += __shfl_down(sum, off, 64);
            cnt += __shfl_down(cnt, off, 64);
        }
        if (lane == 0 && cnt > 0.0f) {
            loc_sum += sum / cnt;
            loc_has += 1.0f;
        }
        __syncthreads();                     // smem reused next iteration
    }

    // per-block combine (deterministic, no atomics)
    if (lane == 0) { wsum[wv] = loc_sum; wcnt[wv] = loc_has; }
    __syncthreads();
    if (threadIdx.x == 0) {
        float s = 0.0f, c = 0.0f;
        #pragma unroll
        for (int w = 0; w < WPB; ++w) { s += wsum[w]; c += wcnt[w]; }
        partial[blockIdx.x] = make_float2(s, c);
    }
}

__global__ __launch_bounds__(256)
void prl_reduce(const float2* __restrict__ partial, float* __restrict__ out, int n)
{
    __shared__ float ss[4], sc[4];
    const int lane = threadIdx.x & 63;
    const int wv   = threadIdx.x >> 6;

    float s = 0.0f, c = 0.0f;
    for (int i = threadIdx.x; i < n; i += 256) {
        const float2 p = partial[i];
        s += p.x; c += p.y;
    }
    #pragma unroll
    for (int off = 32; off > 0; off >>= 1) {
        s += __shfl_down(s, off, 64);
        c += __shfl_down(c, off, 64);
    }
    if (lane == 0) { ss[wv] = s; sc[wv] = c; }
    __syncthreads();
    if (threadIdx.x == 0) {
        float ts = ss[0] + ss[1] + ss[2] + ss[3];
        float tc = sc[0] + sc[1] + sc[2] + sc[3];
        out[0] = (tc > 0.0f) ? ts / tc : 0.0f;
    }
}

extern "C" void kernel_launch(void* const* d_in, const int* in_sizes, int n_in,
                              void* d_out, int out_size, void* d_ws, size_t ws_size,
                              hipStream_t stream)
{
    const float* scores   = (const float*)d_in[0];
    const int*   rankings = (const int*)d_in[1];
    const int*   mask     = (const int*)d_in[2];
    const int B = in_sizes[0] / H;

    float2* partial = (float2*)d_ws;    // BLOCKS float2 slots, all written by kernel 1

    prl_races<<<BLOCKS, WPB * 64, 0, stream>>>(scores, rankings, mask, partial, B);
    prl_reduce<<<1, 256, 0, stream>>>(partial, (float*)d_out, BLOCKS);
}

// Round 3
// 74.425 us; speedup vs baseline: 6.4761x; 1.0287x over previous
//
#include <hip/hip_runtime.h>

#define H 64
#define WPB 4       // waves per block
#define RPW 2       // races per wave -> grid = B/8 = 2048 blocks = 8 blocks/CU exactly

typedef _Float16 h2 __attribute__((ext_vector_type(2)));
typedef _Float16 __attribute__((may_alias)) f16a;

union U32H2 { unsigned int u; h2 h; };

__global__ __launch_bounds__(WPB * 64)
void prl_races(const float* __restrict__ scores,
               const int* __restrict__ rankings,
               const int* __restrict__ mask,
               float2* __restrict__ partial, int B)
{
    // Per wave, per race: 16 x uint4. Layout of group g (horses 4g..4g+3):
    //   .x = half2(s_{4g}, s_{4g+1})  .y = half2(s_{4g+2}, s_{4g+3})
    //   .z = half2(k_{4g}, k_{4g+1})  .w = half2(k_{4g+2}, k_{4g+3})
    __shared__ uint4 smem[WPB][RPW][H / 4];
    __shared__ float wsum[WPB], wcnt[WPB];

    const int lane   = threadIdx.x & 63;
    const int wv     = threadIdx.x >> 6;
    const int gwave  = blockIdx.x * WPB + wv;
    const int nwaves = gridDim.x * WPB;

    float s[RPW]; int key[RPW];
    #pragma unroll
    for (int it = 0; it < RPW; ++it) {
        const int race = gwave + it * nwaves;
        s[it] = 0.0f; key[it] = 0;
        if (race < B) {
            const int idx = race * H + lane;
            s[it] = scores[idx];
            const int r = rankings[idx];
            const int m = mask[idx];
            key[it] = (m != 0 && r > 0) ? r : 0;
        }
        // stage this race (wave-private LDS region -> NO __syncthreads needed;
        // same-wave write->read ordering is enforced by lgkmcnt waits)
        char* wbase = (char*)&smem[wv][it][0];
        const int g = lane >> 2, sl = (lane & 3) * 2;
        *(f16a*)(wbase + g * 16 + sl)     = (_Float16)s[it];
        *(f16a*)(wbase + g * 16 + 8 + sl) = (_Float16)(float)key[it];
    }

    float loc_sum = 0.0f, loc_has = 0.0f;

    #pragma unroll
    for (int it = 0; it < RPW; ++it) {
        const h2 t2   = (h2)(_Float16)(1.0f - s[it]);      // hinge = max(t + s_j, 0)
        const h2 ki2  = (h2)(_Float16)(float)key[it];
        const h2 zero = (h2)(_Float16)0.0f;
        const h2 one  = (h2)(_Float16)1.0f;

        float sumA = 0.0f, sumB = 0.0f;    // two chains for ILP
        h2 cntA = zero, cntB = zero;       // pair counts are small ints: exact in fp16

        #pragma unroll
        for (int g = 0; g < H / 4; ++g) {
            const uint4 q = smem[wv][it][g];   // wave-uniform -> LDS broadcast, 4 horses
            U32H2 ux, uy, uz, uw;
            ux.u = q.x; uy.u = q.y; uz.u = q.z; uw.u = q.w;
            const h2 hA = __builtin_elementwise_max(t2 + ux.h, zero);
            const h2 hB = __builtin_elementwise_max(t2 + uy.h, zero);
            // pair predicate: 1.0 iff k_j - k_i >= 1 (keys are small exact ints)
            const h2 pA = __builtin_elementwise_min(__builtin_elementwise_max(uz.h - ki2, zero), one);
            const h2 pB = __builtin_elementwise_min(__builtin_elementwise_max(uw.h - ki2, zero), one);
#if __has_builtin(__builtin_amdgcn_fdot2)
            sumA = __builtin_amdgcn_fdot2(hA, pA, sumA, false);
            sumB = __builtin_amdgcn_fdot2(hB, pB, sumB, false);
#else
            sumA += (float)hA.x * (float)pA.x + (float)hA.y * (float)pA.y;
            sumB += (float)hB.x * (float)pB.x + (float)hB.y * (float)pB.y;
#endif
            cntA = cntA + pA;
            cntB = cntB + pB;
        }

        float sum = sumA + sumB;
        const h2 c2 = cntA + cntB;
        float cnt = (float)c2.x + (float)c2.y;
        if (key[it] == 0) { sum = 0.0f; cnt = 0.0f; }   // invalid-i lanes

        #pragma unroll
        for (int off = 32; off > 0; off >>= 1) {
            sum += __shfl_down(sum, off, 64);
            cnt += __shfl_down(cnt, off, 64);
        }
        if (lane == 0 && cnt > 0.0f) {
            loc_sum += sum / cnt;
            loc_has += 1.0f;
        }
    }

    // per-block combine (the only cross-wave communication)
    if (lane == 0) { wsum[wv] = loc_sum; wcnt[wv] = loc_has; }
    __syncthreads();
    if (threadIdx.x == 0) {
        float ps = 0.0f, pc = 0.0f;
        #pragma unroll
        for (int w = 0; w < WPB; ++w) { ps += wsum[w]; pc += wcnt[w]; }
        partial[blockIdx.x] = make_float2(ps, pc);
    }
}

__global__ __launch_bounds__(256)
void prl_reduce(const float2* __restrict__ partial, float* __restrict__ out, int n)
{
    __shared__ float ss[4], sc[4];
    const int lane = threadIdx.x & 63;
    const int wv   = threadIdx.x >> 6;

    float s = 0.0f, c = 0.0f;
    for (int i = threadIdx.x; i < n; i += 256) {
        const float2 p = partial[i];
        s += p.x; c += p.y;
    }
    #pragma unroll
    for (int off = 32; off > 0; off >>= 1) {
        s += __shfl_down(s, off, 64);
        c += __shfl_down(c, off, 64);
    }
    if (lane == 0) { ss[wv] = s; sc[wv] = c; }
    __syncthreads();
    if (threadIdx.x == 0) {
        const float ts = ss[0] + ss[1] + ss[2] + ss[3];
        const float tc = sc[0] + sc[1] + sc[2] + sc[3];
        out[0] = (tc > 0.0f) ? ts / tc : 0.0f;
    }
}

extern "C" void kernel_launch(void* const* d_in, const int* in_sizes, int n_in,
                              void* d_out, int out_size, void* d_ws, size_t ws_size,
                              hipStream_t stream)
{
    const float* scores   = (const float*)d_in[0];
    const int*   rankings = (const int*)d_in[1];
    const int*   mask     = (const int*)d_in[2];
    const int B = in_sizes[0] / H;

    float2* partial = (float2*)d_ws;   // one slot per block, all written

    const int grid = (B + WPB * RPW - 1) / (WPB * RPW);   // 2048 at B=16384
    prl_races<<<grid, WPB * 64, 0, stream>>>(scores, rankings, mask, partial, B);
    prl_reduce<<<1, 256, 0, stream>>>(partial, (float*)d_out, grid);
}

// Round 4
// 72.224 us; speedup vs baseline: 6.6735x; 1.0305x over previous
//
#include <hip/hip_runtime.h>

#define H 64
#define WPB 4       // waves per block
#define RPW 2       // races per wave -> grid = B/8 = 2048 blocks = 8 blocks/CU

typedef _Float16 h2 __attribute__((ext_vector_type(2)));
typedef _Float16 __attribute__((may_alias)) f16a;

union U32H2 { unsigned int u; h2 h; };

// ---- wave64 sum via DPP (rocPRIM pattern). Result uniform via readlane(63).
// old=0 => lanes with disabled/invalid source add 0 (identity). ~60 cyc vs
// ~400+ for the __shfl_down ds_bpermute chain.
__device__ __forceinline__ float dpp_add(float x, const int ctrl, const int rmask) {
    int y;
    switch (ctrl) {   // builtin requires literal ctrl/masks
    case 0x111: y = __builtin_amdgcn_update_dpp(0, __float_as_int(x), 0x111, 0xf, 0xf, false); break;
    case 0x112: y = __builtin_amdgcn_update_dpp(0, __float_as_int(x), 0x112, 0xf, 0xf, false); break;
    case 0x114: y = __builtin_amdgcn_update_dpp(0, __float_as_int(x), 0x114, 0xf, 0xf, false); break;
    case 0x118: y = __builtin_amdgcn_update_dpp(0, __float_as_int(x), 0x118, 0xf, 0xf, false); break;
    case 0x142: y = __builtin_amdgcn_update_dpp(0, __float_as_int(x), 0x142, 0xa, 0xf, false); break;
    default:    y = __builtin_amdgcn_update_dpp(0, __float_as_int(x), 0x143, 0xc, 0xf, false); break;
    }
    return x + __int_as_float(y);
}
__device__ __forceinline__ float wave_total(float x) {
    x = dpp_add(x, 0x111, 0xf);   // row_shr:1
    x = dpp_add(x, 0x112, 0xf);   // row_shr:2
    x = dpp_add(x, 0x114, 0xf);   // row_shr:4
    x = dpp_add(x, 0x118, 0xf);   // row_shr:8 -> lane15 of each row = row sum
    x = dpp_add(x, 0x142, 0xa);   // row_bcast:15 -> lane31/63 = half sums
    x = dpp_add(x, 0x143, 0xc);   // row_bcast:31 -> lane63 = total
    return __int_as_float(__builtin_amdgcn_readlane(__float_as_int(x), 63));
}

__global__ __launch_bounds__(WPB * 64)
void prl_races(const float* __restrict__ scores,
               const int* __restrict__ rankings,
               const int* __restrict__ mask,
               float2* __restrict__ partial, int B)
{
    // Per wave, per race: 16 x uint4; group g = horses 4g..4g+3:
    //   .x = half2(s,s) .y = half2(s,s) .z = half2(k,k) .w = half2(k,k)
    __shared__ uint4 smem[WPB][RPW][H / 4];
    __shared__ float wsum[WPB], wcnt[WPB];

    const int lane   = threadIdx.x & 63;
    const int wv     = threadIdx.x >> 6;
    const int gwave  = blockIdx.x * WPB + wv;
    const int nwaves = gridDim.x * WPB;

    float s[RPW]; int key[RPW];
    #pragma unroll
    for (int it = 0; it < RPW; ++it) {
        const int race = gwave + it * nwaves;
        s[it] = 0.0f; key[it] = 0;
        if (race < B) {
            const int idx = race * H + lane;
            s[it] = scores[idx];
            const int r = rankings[idx];
            const int m = mask[idx];
            key[it] = (m != 0 && r > 0) ? r : 0;
        }
        // wave-private LDS region -> no __syncthreads; same-wave write->read
        // ordering enforced by compiler lgkmcnt waits
        char* wbase = (char*)&smem[wv][it][0];
        const int g = lane >> 2, sl = (lane & 3) * 2;
        *(f16a*)(wbase + g * 16 + sl)     = (_Float16)s[it];
        *(f16a*)(wbase + g * 16 + 8 + sl) = (_Float16)(float)key[it];
    }

    float loc_sum = 0.0f, loc_has = 0.0f;

    #pragma unroll
    for (int it = 0; it < RPW; ++it) {
        const h2 t2   = (h2)(_Float16)(1.0f - s[it]);   // hinge = max(t + s_j, 0)
        const h2 ki2  = (h2)(_Float16)(float)key[it];
        const h2 zero = (h2)(_Float16)0.0f;
        const h2 one  = (h2)(_Float16)1.0f;

        float sumA = 0.0f, sumB = 0.0f;
        h2 cntA = zero, cntB = zero;   // small exact ints in fp16

        #pragma unroll
        for (int g = 0; g < H / 4; ++g) {
            const uint4 q = smem[wv][it][g];   // wave-uniform -> LDS broadcast
            U32H2 ux, uy, uz, uw;
            ux.u = q.x; uy.u = q.y; uz.u = q.z; uw.u = q.w;
            const h2 hA = __builtin_elementwise_max(t2 + ux.h, zero);
            const h2 hB = __builtin_elementwise_max(t2 + uy.h, zero);
            const h2 pA = __builtin_elementwise_min(__builtin_elementwise_max(uz.h - ki2, zero), one);
            const h2 pB = __builtin_elementwise_min(__builtin_elementwise_max(uw.h - ki2, zero), one);
#if __has_builtin(__builtin_amdgcn_fdot2)
            sumA = __builtin_amdgcn_fdot2(hA, pA, sumA, false);
            sumB = __builtin_amdgcn_fdot2(hB, pB, sumB, false);
#else
            sumA += (float)hA.x * (float)pA.x + (float)hA.y * (float)pA.y;
            sumB += (float)hB.x * (float)pB.x + (float)hB.y * (float)pB.y;
#endif
            cntA = cntA + pA;
            cntB = cntB + pB;
        }

        float sum = sumA + sumB;
        const h2 c2 = cntA + cntB;
        float cnt = (float)c2.x + (float)c2.y;
        if (key[it] == 0) { sum = 0.0f; cnt = 0.0f; }   // invalid-i lanes

        const float tsum = wave_total(sum);   // uniform across wave
        const float tcnt = wave_total(cnt);
        if (tcnt > 0.0f) {                    // uniform branch
            loc_sum += tsum / tcnt;
            loc_has += 1.0f;
        }
    }

    // per-block combine (the only cross-wave communication)
    if (lane == 0) { wsum[wv] = loc_sum; wcnt[wv] = loc_has; }
    __syncthreads();
    if (threadIdx.x == 0) {
        float ps = 0.0f, pc = 0.0f;
        #pragma unroll
        for (int w = 0; w < WPB; ++w) { ps += wsum[w]; pc += wcnt[w]; }
        partial[blockIdx.x] = make_float2(ps, pc);
    }
}

__global__ __launch_bounds__(512)
void prl_reduce(const float2* __restrict__ partial, float* __restrict__ out, int n)
{
    __shared__ float ss[8], sc[8];
    const int lane = threadIdx.x & 63;
    const int wv   = threadIdx.x >> 6;

    float s = 0.0f, c = 0.0f;
    #pragma unroll 4
    for (int i = threadIdx.x; i < n; i += 512) {   // 4 independent loads at n=2048
        const float2 p = partial[i];
        s += p.x; c += p.y;
    }
    const float ws = wave_total(s);
    const float wc = wave_total(c);
    if (lane == 0) { ss[wv] = ws; sc[wv] = wc; }
    __syncthreads();
    if (threadIdx.x == 0) {
        float ts = 0.0f, tc = 0.0f;
        #pragma unroll
        for (int w = 0; w < 8; ++w) { ts += ss[w]; tc += sc[w]; }
        out[0] = (tc > 0.0f) ? ts / tc : 0.0f;
    }
}

extern "C" void kernel_launch(void* const* d_in, const int* in_sizes, int n_in,
                              void* d_out, int out_size, void* d_ws, size_t ws_size,
                              hipStream_t stream)
{
    const float* scores   = (const float*)d_in[0];
    const int*   rankings = (const int*)d_in[1];
    const int*   mask     = (const int*)d_in[2];
    const int B = in_sizes[0] / H;

    float2* partial = (float2*)d_ws;   // one slot per block, all written

    const int grid = (B + WPB * RPW - 1) / (WPB * RPW);   // 2048 at B=16384
    prl_races<<<grid, WPB * 64, 0, stream>>>(scores, rankings, mask, partial, B);
    prl_reduce<<<1, 512, 0, stream>>>(partial, (float*)d_out, grid);
}